// Round 7
// baseline (160.066 us; speedup 1.0000x reference)
//
#include <hip/hip_runtime.h>
#include <cfloat>
#include <math.h>

#define D_IN 128
#define D_OUT 64
#define NEG_SLOPE 0.2f
#define TM 64    // rows per block in linear kernel
#define ROWF 96  // floats per hkv row: 64 f32 (hk) + 64 bf16 (hv) = 384 B

// bf16 pack (RNE) / unpack helpers --------------------------------------------
__device__ __forceinline__ unsigned short f2bf(float x) {
  union { float f; unsigned u; } a; a.f = x;
  unsigned r = a.u + 0x7FFFu + ((a.u >> 16) & 1u);
  return (unsigned short)(r >> 16);
}
__device__ __forceinline__ float4 unpack4(uint2 q) {
  union { unsigned u; float f; } t;
  float4 r;
  t.u = q.x << 16;          r.x = t.f;
  t.u = q.x & 0xFFFF0000u;  r.y = t.f;
  t.u = q.y << 16;          r.z = t.f;
  t.u = q.y & 0xFFFF0000u;  r.w = t.f;
  return r;
}

__device__ __forceinline__ void fma4(float acc[4], const float4& xv,
                                     const float4& w0, const float4& w1,
                                     const float4& w2, const float4& w3) {
  acc[0] += xv.x * w0.x + xv.y * w1.x + xv.z * w2.x + xv.w * w3.x;
  acc[1] += xv.x * w0.y + xv.y * w1.y + xv.z * w2.y + xv.w * w3.y;
  acc[2] += xv.x * w0.z + xv.y * w1.z + xv.z * w2.z + xv.w * w3.z;
  acc[3] += xv.x * w0.w + xv.y * w1.w + xv.z * w2.w + xv.w * w3.w;
}

// ---------------------------------------------------------------------------
// Kernel A (fused K+V): H = X @ W + b.
// Row layout: hkv[r] = [64 f32 of hk | 64 bf16 of hv]  (384 B, 3 cache lines)
// blockIdx < nblk: key half (f32), else value half (bf16).
// Thread (tc=t&15, tr=t>>4) computes 4 rows x 4 cols. Software-pipelined:
// X float4s and W LDS quads for k4+1 prefetched while k4's FMAs issue.
// ---------------------------------------------------------------------------
__global__ __launch_bounds__(256) void linear_kernel(
    const float* __restrict__ Xk, const float* __restrict__ Xv,
    const float* __restrict__ Wk, const float* __restrict__ bk,
    const float* __restrict__ Wv, const float* __restrict__ bv,
    float* __restrict__ hkv, int R, int nblk) {
  const int which = (blockIdx.x >= nblk) ? 1 : 0;
  const int blk = blockIdx.x - which * nblk;
  const float* __restrict__ X = which ? Xv : Xk;
  const float* __restrict__ W = which ? Wv : Wk;
  const float* __restrict__ bias = which ? bv : bk;

  __shared__ float Wl[D_IN * D_OUT];  // 32 KB, [k][col]
  __shared__ float bl[D_OUT];
  for (int i = threadIdx.x; i < D_IN * D_OUT / 4; i += 256)
    reinterpret_cast<float4*>(Wl)[i] = reinterpret_cast<const float4*>(W)[i];
  if (threadIdx.x < D_OUT) bl[threadIdx.x] = bias[threadIdx.x];
  __syncthreads();

  const int tc = threadIdx.x & 15;   // col quad
  const int tr = threadIdx.x >> 4;   // row quad
  const int r0 = blk * TM + tr * 4;
  if (r0 >= R) return;
  const int rmax = (r0 + 4 <= R) ? 4 : (R - r0);

  const float4* xr[4];
#pragma unroll
  for (int i = 0; i < 4; ++i)
    xr[i] = reinterpret_cast<const float4*>(
        X + (size_t)(r0 + (i < rmax ? i : 0)) * D_IN);
  const float4* wq = reinterpret_cast<const float4*>(Wl) + tc;  // stride 16

  const float4 bv4 = reinterpret_cast<float4*>(bl)[tc];
  float acc[4][4];
#pragma unroll
  for (int i = 0; i < 4; ++i) {
    acc[i][0] = bv4.x; acc[i][1] = bv4.y; acc[i][2] = bv4.z; acc[i][3] = bv4.w;
  }

  // pipeline prologue: current X and W for k4=0
  float4 xc[4], xn[4];
#pragma unroll
  for (int i = 0; i < 4; ++i) xc[i] = xr[i][0];
  float4 wc0 = wq[0 * 16], wc1 = wq[1 * 16], wc2 = wq[2 * 16], wc3 = wq[3 * 16];
  float4 wn0, wn1, wn2, wn3;

  for (int k4 = 0; k4 < D_IN / 4 - 1; ++k4) {
    // prefetch k4+1 (global X + LDS W) before issuing this iteration's FMAs
#pragma unroll
    for (int i = 0; i < 4; ++i) xn[i] = xr[i][k4 + 1];
    const float4* wqn = wq + (k4 + 1) * 64;  // (k4+1)*4 rows of 16 quads
    wn0 = wqn[0 * 16]; wn1 = wqn[1 * 16]; wn2 = wqn[2 * 16]; wn3 = wqn[3 * 16];
#pragma unroll
    for (int i = 0; i < 4; ++i) fma4(acc[i], xc[i], wc0, wc1, wc2, wc3);
#pragma unroll
    for (int i = 0; i < 4; ++i) xc[i] = xn[i];
    wc0 = wn0; wc1 = wn1; wc2 = wn2; wc3 = wn3;
  }
#pragma unroll
  for (int i = 0; i < 4; ++i) fma4(acc[i], xc[i], wc0, wc1, wc2, wc3);

#pragma unroll
  for (int i = 0; i < 4; ++i) {
    if (i >= rmax) break;
    float* row = hkv + (size_t)(r0 + i) * ROWF;
    if (which == 0) {
      float4 o = {acc[i][0], acc[i][1], acc[i][2], acc[i][3]};
      reinterpret_cast<float4*>(row)[tc] = o;
    } else {
      ushort4 o;
      o.x = f2bf(acc[i][0]); o.y = f2bf(acc[i][1]);
      o.z = f2bf(acc[i][2]); o.w = f2bf(acc[i][3]);
      *reinterpret_cast<ushort4*>(
          reinterpret_cast<unsigned short*>(row + D_OUT) + 4 * tc) = o;
    }
  }
}

// ---------------------------------------------------------------------------
// Kernel B: CSR row pointers from sorted dst. row_ptr[i] = lower_bound(dst, i)
// ---------------------------------------------------------------------------
__global__ void rowptr_kernel(const int* __restrict__ dst, int E, int N,
                              int* __restrict__ row_ptr) {
  int i = blockIdx.x * blockDim.x + threadIdx.x;
  if (i > N) return;
  int lo = 0, hi = E;
  while (lo < hi) {
    int mid = (lo + hi) >> 1;
    if (dst[mid] < i) lo = mid + 1; else hi = mid;
  }
  row_ptr[i] = lo;
}

// ---------------------------------------------------------------------------
// sum over each 16-lane row via DPP rotate-adds (pure VALU).
// ---------------------------------------------------------------------------
__device__ __forceinline__ float rowsum16(float p) {
  union { float f; int i; } u, v;
  u.f = p;
  v.i = __builtin_amdgcn_update_dpp(0, u.i, 0x121, 0xF, 0xF, true);  // row_ror:1
  u.f += v.f;
  v.i = __builtin_amdgcn_update_dpp(0, u.i, 0x122, 0xF, 0xF, true);  // row_ror:2
  u.f += v.f;
  v.i = __builtin_amdgcn_update_dpp(0, u.i, 0x124, 0xF, 0xF, true);  // row_ror:4
  u.f += v.f;
  v.i = __builtin_amdgcn_update_dpp(0, u.i, 0x128, 0xF, 0xF, true);  // row_ror:8
  u.f += v.f;
  return u.f;
}

struct SMState { float m, l; float4 a; };

__device__ __forceinline__ void sm_update(SMState& st, float p, float4 vs) {
  const float mn = fmaxf(st.m, p);
  const float sc = __expf(st.m - mn);
  const float a = __expf(p - mn);
  st.l = st.l * sc + a;
  st.a.x = st.a.x * sc + a * vs.x;
  st.a.y = st.a.y * sc + a * vs.y;
  st.a.z = st.a.z * sc + a * vs.z;
  st.a.w = st.a.w * sc + a * vs.w;
  st.m = mn;
}

__device__ __forceinline__ void sm_merge(SMState& d, const SMState& s) {
  const float mn = fmaxf(d.m, s.m);
  const float s1 = __expf(d.m - mn);
  const float s2 = __expf(s.m - mn);
  d.l = d.l * s1 + s.l * s2;
  d.a.x = d.a.x * s1 + s.a.x * s2;
  d.a.y = d.a.y * s1 + s.a.y * s2;
  d.a.z = d.a.z * s1 + s.a.z * s2;
  d.a.w = d.a.w * s1 + s.a.w * s2;
  d.m = mn;
}

__device__ __forceinline__ void sm_merge_xor(SMState& d, int off) {
  SMState s;
  s.m = __shfl_xor(d.m, off, 64);
  s.l = __shfl_xor(d.l, off, 64);
  s.a.x = __shfl_xor(d.a.x, off, 64);
  s.a.y = __shfl_xor(d.a.y, off, 64);
  s.a.z = __shfl_xor(d.a.z, off, 64);
  s.a.w = __shfl_xor(d.a.w, off, 64);
  sm_merge(d, s);
}

__device__ __forceinline__ void edge_proc(const float* __restrict__ hb, int s,
                                          int li, const float4& kd,
                                          SMState& st) {
  const float* row = hb + (size_t)s * ROWF;
  const float4 ks = reinterpret_cast<const float4*>(row)[li];
  const float4 vs = unpack4(reinterpret_cast<const uint2*>(row + D_OUT)[li]);
  float p = ks.x * kd.x + ks.y * kd.y + ks.z * kd.z + ks.w * kd.w;
  p = rowsum16(p);
  sm_update(st, p, vs);
}

// ---------------------------------------------------------------------------
// Kernel C: per-node segmented online-softmax aggregation, BOTH batches per
// wave. 4 groups of 16 lanes; per group 2 ILP states x 2 batches = 4
// independent chains. hk gathered f32 (exact scores), hv bf16.
// ---------------------------------------------------------------------------
__global__ __launch_bounds__(256) void aggregate_kernel(
    const float* __restrict__ hkv, const int* __restrict__ src,
    const int* __restrict__ row_ptr, float* __restrict__ out, int N) {
  const int node = blockIdx.x * 4 + (threadIdx.x >> 6);
  const int lane = threadIdx.x & 63;
  if (node >= N) return;
  const float* hb0 = hkv;
  const float* hb1 = hkv + (size_t)N * ROWF;

  const int li = lane & 15;  // dim-quad index
  const int g = lane >> 4;   // edge group

  const float4 kd0 = reinterpret_cast<const float4*>(hb0 + (size_t)node * ROWF)[li];
  const float4 kd1 = reinterpret_cast<const float4*>(hb1 + (size_t)node * ROWF)[li];
  const int e0 = row_ptr[node];
  const int e1 = row_ptr[node + 1];

  SMState A0 = {-FLT_MAX, 0.f, {0.f, 0.f, 0.f, 0.f}};
  SMState B0 = A0, A1 = A0, B1 = A0;

  int e = e0 + g;
  for (; e + 4 < e1; e += 8) {
    const int sA = src[e];
    const int sB = src[e + 4];
    edge_proc(hb0, sA, li, kd0, A0);
    edge_proc(hb1, sA, li, kd1, A1);
    edge_proc(hb0, sB, li, kd0, B0);
    edge_proc(hb1, sB, li, kd1, B1);
  }
  if (e < e1) {
    const int sA = src[e];
    edge_proc(hb0, sA, li, kd0, A0);
    edge_proc(hb1, sA, li, kd1, A1);
  }

  sm_merge(A0, B0);
  sm_merge(A1, B1);
  sm_merge_xor(A0, 16); sm_merge_xor(A0, 32);
  sm_merge_xor(A1, 16); sm_merge_xor(A1, 32);

  if (lane < 16) {
#pragma unroll
    for (int b = 0; b < 2; ++b) {
      const SMState& S = b ? A1 : A0;
      const float denom = (S.l == 0.f) ? 1.f : S.l;
      float4 o;
      o.x = S.a.x / denom; o.y = S.a.y / denom;
      o.z = S.a.z / denom; o.w = S.a.w / denom;
      o.x = (o.x >= 0.f) ? o.x : NEG_SLOPE * o.x;
      o.y = (o.y >= 0.f) ? o.y : NEG_SLOPE * o.y;
      o.z = (o.z >= 0.f) ? o.z : NEG_SLOPE * o.z;
      o.w = (o.w >= 0.f) ? o.w : NEG_SLOPE * o.w;
      *reinterpret_cast<float4*>(out + ((size_t)b * N + node) * D_OUT + 4 * lane) = o;
    }
  }
}

// ---------------------------------------------------------------------------
extern "C" void kernel_launch(void* const* d_in, const int* in_sizes, int n_in,
                              void* d_out, int out_size, void* d_ws,
                              size_t ws_size, hipStream_t stream) {
  const float* X_key   = (const float*)d_in[0];
  const float* X_value = (const float*)d_in[1];
  const float* Wk      = (const float*)d_in[2];
  const float* bk      = (const float*)d_in[3];
  const float* Wv      = (const float*)d_in[4];
  const float* bv      = (const float*)d_in[5];
  const int*   src     = (const int*)d_in[6];
  const int*   dst     = (const int*)d_in[7];
  float* out = (float*)d_out;

  const int B = 2;
  const int R = in_sizes[0] / D_IN;  // B*N rows
  const int N = R / B;
  const int E = in_sizes[6];

  // workspace: hkv [R][96] f32-units (64 f32 hk | 64 bf16 hv) | row_ptr
  float* hkv = (float*)d_ws;
  int* row_ptr = (int*)(hkv + (size_t)R * ROWF);

  const int blocksB = (N + 1 + 255) / 256;
  hipLaunchKernelGGL(rowptr_kernel, dim3(blocksB), dim3(256), 0, stream,
                     dst, E, N, row_ptr);
  const int nblk = (R + TM - 1) / TM;
  hipLaunchKernelGGL(linear_kernel, dim3(2 * nblk), dim3(256), 0, stream,
                     X_key, X_value, Wk, bk, Wv, bv, hkv, R, nblk);
  const int blocksC = (N + 3) / 4;  // one wave per node, both batches
  hipLaunchKernelGGL(aggregate_kernel, dim3(blocksC), dim3(256), 0, stream,
                     hkv, src, row_ptr, out, N);
}